// Round 4
// baseline (630.089 us; speedup 1.0000x reference)
//
#include <hip/hip_runtime.h>
#include <stdint.h>
#include <stddef.h>

typedef _Float16 half_t;
typedef _Float16 half8 __attribute__((ext_vector_type(8)));
typedef float float4v __attribute__((ext_vector_type(4)));

#define D_DIM 1792
#define B_DIM 8192
#define LD D_DIM

// ---------------------------------------------------------------------------
// Async global->LDS staging of ROWS*32 fp16 tile (rows along K, NT layout).
// slot = chunk ^ ((row>>1)&3): every 8-lane b128 phase covers all 8 bank-quads
// (conflict-free — verified: SQ_LDS_BANK_CONFLICT 6.4e6 -> 0).  [gemm_nt path]
// ---------------------------------------------------------------------------
__device__ __forceinline__ void stage_rows(const half_t* __restrict__ src, int row0, int ld,
                                           int k0, half_t* dst, int nchunks, int tid) {
  for (int base = 0; base < nchunks; base += 256) {
    int ch  = base + tid;
    int row = ch >> 2, kc = ch & 3;
    int swz = kc ^ ((row >> 1) & 3);
    const half_t* g = src + (size_t)(row0 + row) * ld + k0 + swz * 8;
    half_t* l = dst + (size_t)(base + (tid & 192)) * 8;   // wave-uniform base; HW adds lane*16B
    __builtin_amdgcn_global_load_lds(
        (const __attribute__((address_space(1))) uint32_t*)(const void*)g,
        (__attribute__((address_space(3))) uint32_t*)(void*)l, 16, 0, 0);
  }
}

__device__ __forceinline__ half8 frag32(const half_t* lds, int row, int chunk) {
  int slot = chunk ^ ((row >> 1) & 3);
  return *(const half8*)(lds + row * 32 + slot * 8);
}
// 128-wide LDS rows (Us / Dinv in the solve): 2-way aliasing only (free).
__device__ __forceinline__ half8 frag128(const half_t* lds, int row, int chunk) {
  int slot = chunk ^ (row & 15);
  return *(const half8*)(lds + row * 128 + slot * 8);
}

// ---------------------------------------------------------------------------
// 1. Row-normalize U -> Vh (fp16). One block per row.
// ---------------------------------------------------------------------------
__global__ __launch_bounds__(256) void normalize_rows(const float* __restrict__ U,
                                                      half_t* __restrict__ Vh) {
  int r = blockIdx.x, t = threadIdx.x;
  float v[7];
  float s = 0.f;
#pragma unroll
  for (int i = 0; i < 7; ++i) {
    v[i] = U[(size_t)r * D_DIM + t + i * 256];
    s += v[i] * v[i];
  }
#pragma unroll
  for (int m = 32; m; m >>= 1) s += __shfl_xor(s, m);
  __shared__ float red[4];
  __shared__ float tot;
  if ((t & 63) == 0) red[t >> 6] = s;
  __syncthreads();
  if (t == 0) tot = 1.0f / sqrtf(red[0] + red[1] + red[2] + red[3]);
  __syncthreads();
  float rn = tot;
#pragma unroll
  for (int i = 0; i < 7; ++i)
    Vh[(size_t)r * D_DIM + t + i * 256] = (half_t)(v[i] * rn);
}

// ---------------------------------------------------------------------------
// 2. Transpose X (fp32, D x B) -> XT (fp16, B x D). 64x64 LDS tiles.
// ---------------------------------------------------------------------------
__global__ __launch_bounds__(256) void transpose_x(const float* __restrict__ X,
                                                   half_t* __restrict__ XT) {
  __shared__ half_t t[64][68];
  int r0 = blockIdx.x * 64, c0 = blockIdx.y * 64;
  int tid = threadIdx.x;
#pragma unroll
  for (int i = 0; i < 16; ++i) {
    int f = tid + i * 256;
    int rr = f >> 6, cc = f & 63;
    t[rr][cc] = (half_t)X[(size_t)(r0 + rr) * B_DIM + c0 + cc];
  }
  __syncthreads();
#pragma unroll
  for (int i = 0; i < 16; ++i) {
    int f = tid + i * 256;
    int cc = f >> 6, rr = f & 63;
    XT[(size_t)(c0 + cc) * D_DIM + r0 + rr] = t[rr][cc];
  }
}

// ---------------------------------------------------------------------------
// 2b. Transpose Vh (fp16, D x D) -> VhT.
// ---------------------------------------------------------------------------
__global__ __launch_bounds__(256) void transpose_h(const half_t* __restrict__ Vh,
                                                   half_t* __restrict__ VhT) {
  __shared__ half_t t[64][68];
  int r0 = blockIdx.x * 64, c0 = blockIdx.y * 64;
  int tid = threadIdx.x;
#pragma unroll
  for (int i = 0; i < 16; ++i) {
    int f = tid + i * 256;
    int rr = f >> 6, cc = f & 63;
    t[rr][cc] = Vh[(size_t)(r0 + rr) * D_DIM + c0 + cc];
  }
  __syncthreads();
#pragma unroll
  for (int i = 0; i < 16; ++i) {
    int f = tid + i * 256;
    int cc = f >> 6, rr = f & 63;
    VhT[(size_t)(c0 + cc) * D_DIM + r0 + rr] = t[rr][cc];
  }
}

// ---------------------------------------------------------------------------
// 3. Big NT MFMA GEMM: acc[m][n] = sum_k A[m][k]*B[n][k], 128x128 tile, BK=32.
//    MODE 0 (gram->T16): triangular block skip; Ch = (c<r) ? 2*acc : 0  (fp16)
//    MODE 1 (Pf build):  Ch = (r==c ? 1 : 0) - acc                      (fp16)
//    MODE 2 (final):     Cf = acc                                       (fp32)
// ---------------------------------------------------------------------------
template <int MODE>
__global__ __launch_bounds__(256) void gemm_nt(const half_t* __restrict__ A,
                                               const half_t* __restrict__ B,
                                               float* __restrict__ Cf, half_t* __restrict__ Ch,
                                               int K, int lda, int ldb, int ldc) {
  int m0 = blockIdx.y * 128, n0 = blockIdx.x * 128;
  if constexpr (MODE == 0) { if (n0 > m0) return; }   // gram: lower+diag blocks only
  __shared__ half_t sA[128 * 32];
  __shared__ half_t sB[128 * 32];
  int tid = threadIdx.x, lane = tid & 63, wave = tid >> 6;
  int ln15 = lane & 15, quad = lane >> 4;
  int wr = (wave & 1) * 64, wc = (wave >> 1) * 64;
  float4v acc[4][4] = {};
  for (int kb = 0; kb < K / 32; ++kb) {
    stage_rows(A, m0, lda, kb * 32, sA, 512, tid);
    stage_rows(B, n0, ldb, kb * 32, sB, 512, tid);
    __syncthreads();
    half8 af[4], bf[4];
#pragma unroll
    for (int i = 0; i < 4; ++i) af[i] = frag32(sA, wr + i * 16 + ln15, quad);
#pragma unroll
    for (int j = 0; j < 4; ++j) bf[j] = frag32(sB, wc + j * 16 + ln15, quad);
#pragma unroll
    for (int i = 0; i < 4; ++i)
#pragma unroll
      for (int j = 0; j < 4; ++j)
        acc[i][j] = __builtin_amdgcn_mfma_f32_16x16x32_f16(af[i], bf[j], acc[i][j], 0, 0, 0);
    __syncthreads();
  }
#pragma unroll
  for (int i = 0; i < 4; ++i)
#pragma unroll
    for (int j = 0; j < 4; ++j)
#pragma unroll
      for (int rg = 0; rg < 4; ++rg) {
        int row = m0 + wr + i * 16 + quad * 4 + rg;
        int col = n0 + wc + j * 16 + ln15;
        size_t idx = (size_t)row * ldc + col;
        float v = acc[i][j][rg];
        if constexpr (MODE == 0) Ch[idx] = (col < row) ? (half_t)(2.0f * v) : (half_t)0.0f;
        else if constexpr (MODE == 1) Ch[idx] = (half_t)(((row == col) ? 1.0f : 0.0f) - v);
        else Cf[idx] = v;
      }
}

// ---------------------------------------------------------------------------
// 4. Invert 14 diagonal 128x128 unit-lower-triangular blocks of T (from T16).
//    One wave per column; forward substitution. -> Dinv (fp16, 14x128x128)
// ---------------------------------------------------------------------------
__global__ __launch_bounds__(256) void diag_inv(const half_t* __restrict__ T16,
                                                half_t* __restrict__ Dinv) {
  int b = blockIdx.x >> 5;        // block 0..13
  int cg = blockIdx.x & 31;       // column group
  int wave = threadIdx.x >> 6, ln = threadIdx.x & 63;
  int c = cg * 4 + wave;          // this wave's column (0..127)
  __shared__ float Ls[128][128];
  __shared__ float xw[4][128];
  for (int i = 0; i < 64; ++i) {
    int f = threadIdx.x + i * 256;
    int r = f >> 7, cc = f & 127;
    Ls[r][cc] = (cc < r) ? (float)T16[(size_t)(b * 128 + r) * D_DIM + b * 128 + cc] : 0.0f;
  }
  __syncthreads();
  float xlo = (ln == 0) ? 1.f : 0.f, xhi = 0.f;
  for (int r = c + 1; r < 128; ++r) {
    float ta = 0.f;
    int j0 = c + ln, j1 = c + 64 + ln;
    if (j0 < r) ta += Ls[r][j0] * xlo;
    if (j1 < r) ta += Ls[r][j1] * xhi;
#pragma unroll
    for (int m = 32; m; m >>= 1) ta += __shfl_xor(ta, m);
    float xr = -ta;
    if (j0 == r) xlo = xr;
    if (j1 == r) xhi = xr;
    if (ln == 0) xw[wave][r] = xr;
  }
  __syncthreads();
  for (int rr = ln; rr < 128; rr += 64) {
    float val = (rr < c) ? 0.f : ((rr == c) ? 1.f : xw[wave][rr]);
    Dinv[(size_t)b * 16384 + (size_t)rr * 128 + c] = (half_t)val;
  }
}

// ---------------------------------------------------------------------------
// 5. FUSED blocked forward substitution — ONE launch.
//    R4: K-loop LDS staging REMOVED. R1/R3 evidence: ~2000cy/iter regardless
//    of ring depth => the compiler's waitcnt pass cannot disambiguate
//    runtime-indexed ring slots against outstanding global_load_lds DMA and
//    conservatively drains every iteration (prefetch defeated). The operand
//    tiles are L2-resident (WtT ~213KB/block, T16 panel <=448KB), so staging
//    buys nothing (lesson: don't stage what caches). Each wave now loads its
//    MFMA fragments DIRECTLY global->VGPR (per-lane 16B vector loads),
//    software-pipelined one BK=64 step ahead with two statically-indexed
//    register groups. Compiler inserts precise counted vmcnt from register
//    deps; NO barriers, NO LDS, NO DMA-alias hazard in the K-loop.
//    Us/sD phase 2-4 structure unchanged (LDS 147KB -> 48KB).
//    Per panel ib:
//      Ut[m][s] = 2*Vn[ib*128+s][m] - sum_{k<ib*128} WtT[m][k]*T16[ib*128+s][k]
//      WtT[m][ib*128+r] = sum_s Ut[m][s]*Dinv[ib][r][s]
// ---------------------------------------------------------------------------
__global__ __launch_bounds__(256, 1) void fused_solve(const half_t* __restrict__ T16,
                                                      const half_t* __restrict__ VhT,
                                                      const half_t* __restrict__ Dinv,
                                                      half_t* __restrict__ WtT) {
  __shared__ half_t Us[64 * 128];              // 16KB (phase 2 -> 4)
  __shared__ half_t sD[128 * 128];             // 32KB (staged at panel top)
  int tid = threadIdx.x, lane = tid & 63, wave = tid >> 6;
  int ln15 = lane & 15, quad = lane >> 4;
  int m0 = blockIdx.x * 64;
  int wr = (wave & 1) * 32, wc = (wave >> 1) * 64;

  // per-lane A-fragment row pointers (fixed across panels)
  const half_t* rowA[2];
#pragma unroll
  for (int i = 0; i < 2; ++i)
    rowA[i] = WtT + (size_t)(m0 + wr + i * 16 + ln15) * D_DIM + quad * 8;

  for (int ib = 0; ib < 14; ++ib) {
    // drain prev panel's WtT stores (vmcnt0+barrier) — visibility for K-loop
    // reads below, and frees Us/sD for this panel's writers.
    __syncthreads();
    // stage Dinv block ib -> sD (one-shot DMA; drained by pre-phase-4 sync)
    for (int it = 0; it < 8; ++it) {
      int ch = it * 256 + tid;
      int row = ch >> 4, sc = ch & 15;
      const half_t* g = Dinv + (size_t)ib * 16384 + (size_t)row * 128 + ((sc ^ (row & 15)) << 3);
      half_t* l = sD + (size_t)(it * 256 + (tid & 192)) * 8;
      __builtin_amdgcn_global_load_lds(
          (const __attribute__((address_space(1))) uint32_t*)(const void*)g,
          (__attribute__((address_space(3))) uint32_t*)(void*)l, 16, 0, 0);
    }
    // per-lane B-fragment row pointers for this panel
    const half_t* rowB[4];
#pragma unroll
    for (int j = 0; j < 4; ++j)
      rowB[j] = T16 + (size_t)(ib * 128 + wc + j * 16 + ln15) * D_DIM + quad * 8;

    float4v acc[2][4] = {};
    int Ksteps = ib * 2;               // BK=64 steps

    half8 Aa[2][2], Ab[4][2], Ba[2][2], Bb[4][2];   // two static reg groups
    auto issue = [&](half8 (&ga)[2][2], half8 (&gb)[4][2], int kb) {
#pragma unroll
      for (int i = 0; i < 2; ++i)
#pragma unroll
        for (int q = 0; q < 2; ++q)
          ga[i][q] = *(const half8*)(rowA[i] + kb * 64 + q * 32);
#pragma unroll
      for (int j = 0; j < 4; ++j)
#pragma unroll
        for (int q = 0; q < 2; ++q)
          gb[j][q] = *(const half8*)(rowB[j] + kb * 64 + q * 32);
    };
    auto domfma = [&](half8 (&ga)[2][2], half8 (&gb)[4][2]) {
#pragma unroll
      for (int q = 0; q < 2; ++q)
#pragma unroll
        for (int i = 0; i < 2; ++i)
#pragma unroll
          for (int j = 0; j < 4; ++j)
            acc[i][j] = __builtin_amdgcn_mfma_f32_16x16x32_f16(ga[i][q], gb[j][q], acc[i][j], 0, 0, 0);
    };
    if (Ksteps > 0) {
      issue(Aa, Ab, 0);
      for (int kb = 0; kb < Ksteps; kb += 2) {   // Ksteps always even
        issue(Ba, Bb, kb + 1);                   // prefetch next while Aa in use
        domfma(Aa, Ab);                          // waits only on Aa/Ab regs
        if (kb + 2 < Ksteps) issue(Aa, Ab, kb + 2);
        domfma(Ba, Bb);
      }
    }
    // phase 2: Ut = 2*VnT - acc  -> Us (A-operand layout, swizzled)
#pragma unroll
    for (int i = 0; i < 2; ++i)
#pragma unroll
      for (int j = 0; j < 4; ++j)
#pragma unroll
        for (int rg = 0; rg < 4; ++rg) {
          int rl = wr + i * 16 + quad * 4 + rg;     // local m
          int cl = wc + j * 16 + ln15;              // local s (panel row)
          float vn = (float)VhT[(size_t)(m0 + rl) * D_DIM + ib * 128 + cl];
          float u = 2.f * vn - acc[i][j][rg];
          int sc = cl >> 3, off = cl & 7;
          Us[rl * 128 + ((sc ^ (rl & 15)) << 3) + off] = (half_t)u;
        }
    __syncthreads();   // full drain: sD DMA (vmcnt) + Us ds_writes visible
    // phase 4: WtT-panel = Ut * Dinv^T  (K=128)
    float4v a2[2][4] = {};
#pragma unroll
    for (int kk = 0; kk < 4; ++kk) {
      half8 af[2], bf[4];
#pragma unroll
      for (int i = 0; i < 2; ++i) af[i] = frag128(Us, wr + i * 16 + ln15, kk * 4 + quad);
#pragma unroll
      for (int j = 0; j < 4; ++j) bf[j] = frag128(sD, wc + j * 16 + ln15, kk * 4 + quad);
#pragma unroll
      for (int i = 0; i < 2; ++i)
#pragma unroll
        for (int j = 0; j < 4; ++j)
          a2[i][j] = __builtin_amdgcn_mfma_f32_16x16x32_f16(af[i], bf[j], a2[i][j], 0, 0, 0);
    }
#pragma unroll
    for (int i = 0; i < 2; ++i)
#pragma unroll
      for (int j = 0; j < 4; ++j)
#pragma unroll
        for (int rg = 0; rg < 4; ++rg) {
          int rl = wr + i * 16 + quad * 4 + rg;
          int cl = wc + j * 16 + ln15;
          WtT[(size_t)(m0 + rl) * D_DIM + ib * 128 + cl] = (half_t)a2[i][j][rg];
        }
  }
}

// ---------------------------------------------------------------------------
extern "C" void kernel_launch(void* const* d_in, const int* in_sizes, int n_in,
                              void* d_out, int out_size, void* d_ws, size_t ws_size,
                              hipStream_t stream) {
  (void)in_sizes; (void)n_in; (void)out_size; (void)ws_size;
  const float* X = (const float*)d_in[0];   // (1792, 8192) fp32
  const float* U = (const float*)d_in[1];   // (1792, 1792) fp32
  float* out = (float*)d_out;               // (1792, 8192) fp32

  char* ws = (char*)d_ws;
  half_t* XT   = (half_t*)(ws);                    // 29,360,128 B
  half_t* Vh   = (half_t*)(ws + 29360128);         //  6,422,528 B
  half_t* VhT  = (half_t*)(ws + 35782656);         //  6,422,528 B
  half_t* T16  = (half_t*)(ws + 42205184);         //  6,422,528 B
  half_t* WtT  = (half_t*)(ws + 48627712);         //  6,422,528 B
  half_t* Dinv = (half_t*)(ws + 55050240);         //    458,752 B
  half_t* Pf   = (half_t*)(ws + 55508992);         //  6,422,528 B  (total ~62 MB)

  normalize_rows<<<dim3(D_DIM), dim3(256), 0, stream>>>(U, Vh);
  transpose_x<<<dim3(D_DIM / 64, B_DIM / 64), dim3(256), 0, stream>>>(X, XT);
  // T16 = 2*strict_tril(Vn Vn^T) directly (gram fused with build_T16; fp32 G gone)
  gemm_nt<0><<<dim3(14, 14), dim3(256), 0, stream>>>(Vh, Vh, nullptr, T16,
                                                     D_DIM, D_DIM, D_DIM, D_DIM);
  transpose_h<<<dim3(28, 28), dim3(256), 0, stream>>>(Vh, VhT);
  diag_inv<<<dim3(448), dim3(256), 0, stream>>>(T16, Dinv);
  // one-launch blocked forward substitution: WtT = (T^{-1} 2Vn)^T
  fused_solve<<<dim3(28), dim3(256), 0, stream>>>(T16, VhT, Dinv, WtT);
  // Pf = I - Wt^T Vn :  Pf[m][n] = delta(m,n) - sum_k WtT[m][k]*VhT[n][k]
  gemm_nt<1><<<dim3(14, 14), dim3(256), 0, stream>>>(WtT, VhT, nullptr, Pf,
                                                     D_DIM, D_DIM, D_DIM, D_DIM);
  // out = Pf X :  out[i][j] = sum_k Pf[i][k]*XT[j][k]
  gemm_nt<2><<<dim3(64, 14), dim3(256), 0, stream>>>(Pf, XT, out, nullptr,
                                                     D_DIM, D_DIM, D_DIM, B_DIM);
}